// Round 2
// 654.423 us; speedup vs baseline: 1.1629x; 1.1629x over previous
//
#include <hip/hip_runtime.h>
#include <hip/hip_bf16.h>

#define NN 200   // nodes
#define BB 256   // batch == attention sequence length
#define DD 128   // d_model == seq
#define DH 32    // head dim
#define NE 1600  // edges
#define LL 2     // layers

typedef short short8 __attribute__((ext_vector_type(8)));
typedef short short4a __attribute__((ext_vector_type(4)));
typedef float floatx4 __attribute__((ext_vector_type(4)));
using bf16 = __hip_bfloat16;

// Inputs fp32 (proven R1-R3); output fp32.

__device__ __forceinline__ short bfs(float x) {
  bf16 h = __float2bfloat16(x);
  return *(short*)&h;
}
__device__ __forceinline__ float b2f(short s) {
  union { unsigned u; float f; } cv;
  cv.u = ((unsigned)(unsigned short)s) << 16;
  return cv.f;
}
__device__ __forceinline__ short8 ldw8(const float* q) {
  float4 a = *(const float4*)q;
  float4 b = *(const float4*)(q + 4);
  short8 r = {bfs(a.x), bfs(a.y), bfs(a.z), bfs(a.w),
              bfs(b.x), bfs(b.y), bfs(b.z), bfs(b.w)};
  return r;
}

// ---------------------------------------------------------------- transpose
__global__ __launch_bounds__(256) void k_transpose(const float* __restrict__ x,
                                                   bf16* __restrict__ X) {
  int tid = blockIdx.x * 256 + threadIdx.x;
  if (tid >= NN * BB * DD) return;
  int d = tid & (DD - 1);
  int rest = tid >> 7;
  int b = rest & (BB - 1);
  int node = rest >> 8;
  X[tid] = (bf16)x[((size_t)b * NN + node) * DD + d];
}

// ---------------------------------------------------------------- node GEMM (plain)
__global__ __launch_bounds__(256) void k_gemm(const bf16* __restrict__ A,
                                              const float* __restrict__ W,
                                              const float* __restrict__ bias,
                                              bf16* __restrict__ out, int nout,
                                              int astride, size_t woff, int wns,
                                              size_t boff, int bns, int relu) {
  int nchunks = nout >> 6;
  int bpn = nchunks << 2;
  int node = blockIdx.x / bpn;
  int t = blockIdx.x - node * bpn;
  int wave = threadIdx.x >> 6;
  int lane = threadIdx.x & 63;
  int tile = t * 4 + wave;
  int nc = tile >> 4;
  int mt = tile & 15;
  int r = lane & 15;
  int quad = lane >> 4;

  const bf16* arow = A + ((size_t)node * BB + mt * 16 + r) * (size_t)astride + quad * 8;
  const float* wrow = W + woff + (size_t)node * (size_t)wns + (size_t)(nc * 64 + r) * DD + quad * 8;

  floatx4 acc[4];
  floatx4 z = {0.f, 0.f, 0.f, 0.f};
#pragma unroll
  for (int s = 0; s < 4; s++) acc[s] = z;

#pragma unroll
  for (int k0 = 0; k0 < DD; k0 += 32) {
    short8 af = *(const short8*)(arow + k0);
#pragma unroll
    for (int s = 0; s < 4; s++) {
      short8 bq = ldw8(wrow + (size_t)s * 16 * DD + k0);
      acc[s] = __builtin_amdgcn_mfma_f32_16x16x32_bf16(af, bq, acc[s], 0, 0, 0);
    }
  }

  const float* bp = bias + boff + (size_t)node * (size_t)bns + nc * 64;
#pragma unroll
  for (int s = 0; s < 4; s++) {
    float bv = bp[s * 16 + r];
#pragma unroll
    for (int i = 0; i < 4; i++) {
      float v = acc[s][i] + bv;
      if (relu) v = v > 0.f ? v : 0.f;
      int row = mt * 16 + quad * 4 + i;
      out[((size_t)node * BB + row) * (size_t)nout + nc * 64 + s * 16 + r] = (bf16)v;
    }
  }
}

// ---------------------------------------------------------------- GEMM + residual + LN
__global__ __launch_bounds__(256) void k_gemm_ln(const bf16* __restrict__ A, int astride,
                                                 const float* __restrict__ W,
                                                 const float* __restrict__ bias,
                                                 bf16* __restrict__ X,
                                                 const float* __restrict__ g,
                                                 const float* __restrict__ be,
                                                 size_t woff, int wns, size_t boff,
                                                 int bns, int gstride) {
  __shared__ float Sm[32 * 128];  // 16 KB
  int node = blockIdx.x >> 3;
  int bt = blockIdx.x & 7;
  int w = threadIdx.x >> 6;
  int lane = threadIdx.x & 63;
  int r = lane & 15, quad = lane >> 4;
  int rt = w & 1;
  int nc = w >> 1;

  const bf16* arow = A + ((size_t)node * BB + bt * 32 + rt * 16 + r) * (size_t)astride + quad * 8;
  const float* wrow = W + woff + (size_t)node * (size_t)wns + (size_t)(nc * 64 + r) * DD + quad * 8;

  floatx4 acc[4];
  floatx4 z = {0.f, 0.f, 0.f, 0.f};
#pragma unroll
  for (int s = 0; s < 4; s++) acc[s] = z;
#pragma unroll
  for (int k0 = 0; k0 < DD; k0 += 32) {
    short8 af = *(const short8*)(arow + k0);
#pragma unroll
    for (int s = 0; s < 4; s++) {
      short8 bq = ldw8(wrow + (size_t)s * 16 * DD + k0);
      acc[s] = __builtin_amdgcn_mfma_f32_16x16x32_bf16(af, bq, acc[s], 0, 0, 0);
    }
  }
  const float* bp = bias + boff + (size_t)node * (size_t)bns + nc * 64;
#pragma unroll
  for (int s = 0; s < 4; s++) {
    float bv = bp[s * 16 + r];
#pragma unroll
    for (int i = 0; i < 4; i++)
      Sm[(rt * 16 + quad * 4 + i) * 128 + nc * 64 + s * 16 + r] = acc[s][i] + bv;
  }
  __syncthreads();

  int row = threadIdx.x >> 3;  // 0..31
  int sub = threadIdx.x & 7;   // col group of 16
  size_t xbase = ((size_t)node * BB + bt * 32 + row) * DD + sub * 16;
  float v[16];
  float sum = 0.f;
#pragma unroll
  for (int j = 0; j < 16; j++) {
    v[j] = Sm[row * 128 + sub * 16 + j] + (float)X[xbase + j];
    sum += v[j];
  }
  sum += __shfl_xor(sum, 1);
  sum += __shfl_xor(sum, 2);
  sum += __shfl_xor(sum, 4);
  float mean = sum * (1.0f / 128.0f);
  float vs = 0.f;
#pragma unroll
  for (int j = 0; j < 16; j++) {
    float c = v[j] - mean;
    vs += c * c;
  }
  vs += __shfl_xor(vs, 1);
  vs += __shfl_xor(vs, 2);
  vs += __shfl_xor(vs, 4);
  float inv = rsqrtf(vs * (1.0f / 128.0f) + 1e-5f);
  const float* gp = g + boff + (size_t)node * gstride + sub * 16;
  const float* bep = be + boff + (size_t)node * gstride + sub * 16;
#pragma unroll
  for (int j = 0; j < 16; j++)
    X[xbase + j] = (bf16)((v[j] - mean) * inv * gp[j] + bep[j]);
}

// ---------------------------------------------------------------- MFMA attention (in-place, Q slot)
__global__ __launch_bounds__(256) void k_attn(bf16* __restrict__ QKV) {
  __shared__ short VT[32 * 264];  // V^T [d][key], padded row stride 264 (16.9 KB)
  __shared__ short Pw[4 * 2560];  // per-wave P / O scratch, [16 rows][40] per qt (10.2 KB)
  int node = blockIdx.x >> 2, h = blockIdx.x & 3;
  int tid = threadIdx.x;
  int wave = tid >> 6, lane = tid & 63, quad = lane >> 4, l15 = lane & 15;
  short* sbase = (short*)(QKV + (size_t)node * BB * 384);

  // stage V^T: VT[d][key] = V[key][d]
  for (int i = tid; i < 4096; i += 256) {
    int key = i >> 4, dp = (i & 15) << 1;
    int two = *(const int*)(sbase + (size_t)key * 384 + 256 + h * 32 + dp);
    VT[dp * 264 + key] = (short)(two & 0xffff);
    VT[(dp + 1) * 264 + key] = (short)(((unsigned)two) >> 16);
  }

  // Q B-frags for this wave's 64 queries (read before any Q-slot write)
  int q0 = wave * 64;
  short8 qf[4];
#pragma unroll
  for (int qt = 0; qt < 4; qt++)
    qf[qt] = *(const short8*)(sbase + (size_t)(q0 + qt * 16 + l15) * 384 + h * 32 + quad * 8);

  __syncthreads();  // VT ready

  floatx4 zz = {0.f, 0.f, 0.f, 0.f};
  floatx4 acc[2][4];
#pragma unroll
  for (int dt = 0; dt < 2; dt++)
#pragma unroll
    for (int qt = 0; qt < 4; qt++) acc[dt][qt] = zz;
  float lp[4] = {0.f, 0.f, 0.f, 0.f};
  const float scale = 0.17677669529663689f;  // 1/sqrt(32)
  short* mypw = &Pw[wave * 2560];

  for (int g = 0; g < 8; g++) {
#pragma unroll
    for (int sub = 0; sub < 2; sub++) {
      int kt = g * 2 + sub;
      short8 kf = *(const short8*)(sbase + (size_t)(kt * 16 + l15) * 384 + 128 + h * 32 + quad * 8);
#pragma unroll
      for (int qt = 0; qt < 4; qt++) {
        floatx4 st = __builtin_amdgcn_mfma_f32_16x16x32_bf16(kf, qf[qt], zz, 0, 0, 0);
        float e0 = __expf(st[0] * scale);
        float e1 = __expf(st[1] * scale);
        float e2 = __expf(st[2] * scale);
        float e3 = __expf(st[3] * scale);
        lp[qt] += (e0 + e1) + (e2 + e3);
        short4a p = {bfs(e0), bfs(e1), bfs(e2), bfs(e3)};
        *(short4a*)(mypw + qt * 640 + l15 * 40 + sub * 16 + quad * 4) = p;
      }
    }
    short8 vf0 = *(const short8*)(&VT[l15 * 264 + g * 32 + quad * 8]);
    short8 vf1 = *(const short8*)(&VT[(16 + l15) * 264 + g * 32 + quad * 8]);
#pragma unroll
    for (int qt = 0; qt < 4; qt++) {
      short8 pf = *(const short8*)(mypw + qt * 640 + l15 * 40 + quad * 8);
      acc[0][qt] = __builtin_amdgcn_mfma_f32_16x16x32_bf16(vf0, pf, acc[0][qt], 0, 0, 0);
      acc[1][qt] = __builtin_amdgcn_mfma_f32_16x16x32_bf16(vf1, pf, acc[1][qt], 0, 0, 0);
    }
  }

  float inv[4];
#pragma unroll
  for (int qt = 0; qt < 4; qt++) {
    float lq = lp[qt];
    lq += __shfl_xor(lq, 16);
    lq += __shfl_xor(lq, 32);
    inv[qt] = 1.0f / lq;
  }

#pragma unroll
  for (int qt = 0; qt < 4; qt++)
#pragma unroll
    for (int dt = 0; dt < 2; dt++)
#pragma unroll
      for (int i = 0; i < 4; i++)
        mypw[(qt * 16 + l15) * 40 + dt * 16 + quad * 4 + i] = bfs(acc[dt][qt][i] * inv[qt]);

#pragma unroll
  for (int r = 0; r < 4; r++) {
    int chunk = r * 64 + lane;
    int query = chunk >> 2, d8 = (chunk & 3) * 8;
    short8 o = *(const short8*)(mypw + query * 40 + d8);
    *(short8*)(sbase + (size_t)(q0 + query) * 384 + h * 32 + d8) = o;
  }
}

// ---------------------------------------------------------------- fold GAT/pred/fc into 4 row-projection vectors
// AS[row]  = X_row . W4[0] + C4[0]   (a_src)
// ADv[row] = X_row . W4[1] + C4[1]   (a_dst)
// HW0[row] = X_row . W4[2] + C4[2]   (h . predW0)
// HW1[row] = X_row . W4[3] + C4[3]   (h . predW1)
// where W4[v] = fcW^T (gatW^T vec_v), C4[v] = fcb . (gatW^T vec_v)
// NOTE: launched AFTER the layer loop — W4/C4 live inside the (then-dead) QKV region.
__global__ __launch_bounds__(256) void k_prep(const float* __restrict__ gatW,
                                              const float* __restrict__ attS,
                                              const float* __restrict__ attD,
                                              const float* __restrict__ predW,
                                              const float* __restrict__ fcW,
                                              const float* __restrict__ fcb,
                                              float* __restrict__ W4,
                                              float* __restrict__ C4) {
  __shared__ float U[4][64];
  int t = threadIdx.x;
  int tt = t >> 6, f = t & 63;
  float u = 0.f;
  if (tt == 0) {
    for (int g = 0; g < 64; g++) u += gatW[g * 64 + f] * attS[g];
  } else if (tt == 1) {
    for (int g = 0; g < 64; g++) u += gatW[g * 64 + f] * attD[g];
  } else if (tt == 2) {
    for (int g = 0; g < 64; g++) u += gatW[g * 64 + f] * predW[g];
  } else {
    for (int g = 0; g < 64; g++) u += gatW[g * 64 + f] * predW[64 + g];
  }
  U[tt][f] = u;
  __syncthreads();
  for (int idx = t; idx < 512; idx += 256) {
    int v = idx >> 7, d = idx & 127;
    float w = 0.f;
#pragma unroll
    for (int ff = 0; ff < 64; ff++) w += fcW[ff * 128 + d] * U[v][ff];
    W4[v * 128 + d] = w;
  }
  if (t < 4) {
    float c = 0.f;
#pragma unroll
    for (int ff = 0; ff < 64; ff++) c += fcb[ff] * U[t][ff];
    C4[t] = c;
  }
}

// ---------------------------------------------------------------- per-row 4 dot products over X
// 8 rows per wave, 8 lanes per row (16 cols each); shfl-xor reduce within row group.
__global__ __launch_bounds__(256) void k_rows(const bf16* __restrict__ X,
                                              const float* __restrict__ W4,
                                              const float* __restrict__ C4,
                                              float* __restrict__ AS,
                                              float* __restrict__ ADv,
                                              float* __restrict__ HW0,
                                              float* __restrict__ HW1) {
  __shared__ float Wl[512];
  int t = threadIdx.x;
  Wl[t] = W4[t];
  Wl[t + 256] = W4[t + 256];
  __syncthreads();
  int wave = t >> 6, lane = t & 63;
  int rrow = lane >> 3, sub = lane & 7;
  int row = blockIdx.x * 32 + wave * 8 + rrow;
  const short* xp = (const short*)(X + (size_t)row * DD) + sub * 16;
  short8 a = *(const short8*)xp;
  short8 b = *(const short8*)(xp + 8);
  float a0 = 0.f, a1 = 0.f, a2 = 0.f, a3 = 0.f;
#pragma unroll
  for (int j = 0; j < 8; j++) {
    float xf = b2f(a[j]);
    int col = sub * 16 + j;
    a0 += xf * Wl[col];
    a1 += xf * Wl[128 + col];
    a2 += xf * Wl[256 + col];
    a3 += xf * Wl[384 + col];
  }
#pragma unroll
  for (int j = 0; j < 8; j++) {
    float xf = b2f(b[j]);
    int col = sub * 16 + 8 + j;
    a0 += xf * Wl[col];
    a1 += xf * Wl[128 + col];
    a2 += xf * Wl[256 + col];
    a3 += xf * Wl[384 + col];
  }
#pragma unroll
  for (int off = 1; off < 8; off <<= 1) {
    a0 += __shfl_xor(a0, off);
    a1 += __shfl_xor(a1, off);
    a2 += __shfl_xor(a2, off);
    a3 += __shfl_xor(a3, off);
  }
  if (sub == 0) {
    AS[row] = a0 + C4[0];
    ADv[row] = a1 + C4[1];
    HW0[row] = a2 + C4[2];
    HW1[row] = a3 + C4[3];
  }
}

// ---------------------------------------------------------------- zero
__global__ __launch_bounds__(256) void k_zero(float4* __restrict__ p, int n4) {
  int i = blockIdx.x * 256 + threadIdx.x;
  if (i < n4) p[i] = make_float4(0.f, 0.f, 0.f, 0.f);
}

// ---------------------------------------------------------------- edges -> 3 scalar accumulators
__global__ __launch_bounds__(256) void k_edge(const int* __restrict__ EI,
                                              const float* __restrict__ AS,
                                              const float* __restrict__ ADv,
                                              const float* __restrict__ HW0,
                                              const float* __restrict__ HW1,
                                              float* __restrict__ NUM0,
                                              float* __restrict__ NUM1,
                                              float* __restrict__ DEN) {
  int tid = blockIdx.x * 256 + threadIdx.x;
  if (tid >= BB * (NE + NN)) return;
  int b = tid / (NE + NN);
  int e = tid - b * (NE + NN);
  int s, d;
  if (e < NE) {
    s = EI[e];
    d = EI[NE + e];
  } else {
    s = d = e - NE;  // self loop
  }
  int js = b * NN + s, jd = b * NN + d;
  float ev = AS[js] + ADv[jd];
  float lr = ev > 0.f ? ev : 0.2f * ev;
  float w = __expf(lr);
  atomicAdd(&NUM0[jd], w * HW0[js]);
  atomicAdd(&NUM1[jd], w * HW1[js]);
  atomicAdd(&DEN[jd], w);
}

// ---------------------------------------------------------------- finalize
__global__ __launch_bounds__(256) void k_fin(const float* __restrict__ NUM0,
                                             const float* __restrict__ NUM1,
                                             const float* __restrict__ DEN,
                                             const float* __restrict__ gatB,
                                             const float* __restrict__ predW,
                                             const float* __restrict__ predB,
                                             float* __restrict__ OUT) {
  int tid = blockIdx.x * 256 + threadIdx.x;
  if (tid >= BB * NN) return;
  float c0 = predB[0], c1 = predB[1];
#pragma unroll
  for (int f = 0; f < 64; f++) {
    float gb = gatB[f];
    c0 += gb * predW[f];
    c1 += gb * predW[64 + f];
  }
  float inv = 1.0f / (DEN[tid] + 1e-16f);
  OUT[2 * tid] = NUM0[tid] * inv + c0;
  OUT[2 * tid + 1] = NUM1[tid] * inv + c1;
}

// ================================================================ launch
extern "C" void kernel_launch(void* const* d_in, const int* in_sizes, int n_in,
                              void* d_out, int out_size, void* d_ws, size_t ws_size,
                              hipStream_t stream) {
  const float* x = (const float*)d_in[0];
  const int* ei = (const int*)d_in[1];
  const float* Wqkv = (const float*)d_in[2];
  const float* bqkv = (const float*)d_in[3];
  const float* Wo = (const float*)d_in[4];
  const float* bo = (const float*)d_in[5];
  const float* g1 = (const float*)d_in[6];
  const float* be1 = (const float*)d_in[7];
  const float* fW1 = (const float*)d_in[8];
  const float* fb1 = (const float*)d_in[9];
  const float* fW2 = (const float*)d_in[10];
  const float* fb2 = (const float*)d_in[11];
  const float* g2 = (const float*)d_in[12];
  const float* be2 = (const float*)d_in[13];
  const float* fcW = (const float*)d_in[14];
  const float* fcb = (const float*)d_in[15];
  const float* gatW = (const float*)d_in[16];
  const float* attS = (const float*)d_in[17];
  const float* attD = (const float*)d_in[18];
  const float* gatB = (const float*)d_in[19];
  const float* predW = (const float*)d_in[20];
  const float* predB = (const float*)d_in[21];

  const size_t NEED = 52428800;
  if (ws_size < NEED) return;  // signature: absmax == max|ref|

  char* ws = (char*)d_ws;
  bf16* X = (bf16*)(ws);                  // [N][B][128]   0 .. 13,107,200
  bf16* QKV = (bf16*)(ws + 13107200);     // [N][B][384]  .. 52,428,800 (reused as H1)
  float* W4 = (float*)(ws + 40960000);    // [4][128]  (written AFTER loop; QKV dead)
  float* C4 = (float*)(ws + 40962048);    // [4]
  float* AS = (float*)(ws + 47513600);    // [51200]
  float* ADv = (float*)(ws + 47718400);   // [51200]
  float* HW0 = (float*)(ws + 47923200);   // [51200]
  float* HW1 = (float*)(ws + 48128000);   // [51200]
  float* NUM0 = (float*)(ws + 48332800);  // [51200]
  float* NUM1 = (float*)(ws + 48537600);  // [51200]
  float* DEN = (float*)(ws + 48742400);   // [51200]

  k_transpose<<<25600, 256, 0, stream>>>(x, X);

  for (int l = 0; l < LL; l++) {
    size_t w3o = (size_t)l * 384 * DD, b3o = (size_t)l * 384;
    size_t wso = (size_t)l * DD * DD, bso = (size_t)l * DD;
    k_gemm<<<24 * NN, 256, 0, stream>>>(X, Wqkv, bqkv, QKV, 384, DD,
                                        w3o, LL * 384 * DD, b3o, LL * 384, 0);
    k_attn<<<NN * 4, 256, 0, stream>>>(QKV);
    k_gemm_ln<<<8 * NN, 256, 0, stream>>>(QKV, 384, Wo, bo, X, g1, be1,
                                          wso, LL * DD * DD, bso, LL * DD, LL * DD);
    k_gemm<<<8 * NN, 256, 0, stream>>>(X, fW1, fb1, QKV, 128, DD,
                                       wso, LL * DD * DD, bso, LL * DD, 1);
    k_gemm_ln<<<8 * NN, 256, 0, stream>>>(QKV, 128, fW2, fb2, X, g2, be2,
                                          wso, LL * DD * DD, bso, LL * DD, LL * DD);
  }

  // QKV dead from here on: W4/C4 (inside the old QKV region) are now safe.
  k_prep<<<1, 256, 0, stream>>>(gatW, attS, attD, predW, fcW, fcb, W4, C4);
  k_rows<<<1600, 256, 0, stream>>>(X, W4, C4, AS, ADv, HW0, HW1);
  k_zero<<<150, 256, 0, stream>>>((float4*)NUM0, 38400);
  k_edge<<<1800, 256, 0, stream>>>(ei, AS, ADv, HW0, HW1, NUM0, NUM1, DEN);
  k_fin<<<200, 256, 0, stream>>>(NUM0, NUM1, DEN, gatB, predW, predB, (float*)d_out);
}

// Round 3
// 535.270 us; speedup vs baseline: 1.4218x; 1.2226x over previous
//
#include <hip/hip_runtime.h>
#include <hip/hip_bf16.h>

#define NN 200   // nodes
#define BB 256   // batch == attention sequence length
#define DD 128   // d_model == seq
#define DH 32    // head dim
#define NE 1600  // edges
#define LL 2     // layers

typedef short short8 __attribute__((ext_vector_type(8)));
typedef short short4a __attribute__((ext_vector_type(4)));
typedef float floatx4 __attribute__((ext_vector_type(4)));
using bf16 = __hip_bfloat16;

// Inputs fp32 (proven R1-R3); output fp32.

__device__ __forceinline__ short bfs(float x) {
  bf16 h = __float2bfloat16(x);
  return *(short*)&h;
}
__device__ __forceinline__ float b2f(short s) {
  union { unsigned u; float f; } cv;
  cv.u = ((unsigned)(unsigned short)s) << 16;
  return cv.f;
}

// ---------------------------------------------------------------- transpose
__global__ __launch_bounds__(256) void k_transpose(const float* __restrict__ x,
                                                   bf16* __restrict__ X) {
  int tid = blockIdx.x * 256 + threadIdx.x;
  if (tid >= NN * BB * DD) return;
  int d = tid & (DD - 1);
  int rest = tid >> 7;
  int b = rest & (BB - 1);
  int node = rest >> 8;
  X[tid] = (bf16)x[((size_t)b * NN + node) * DD + d];
}

// ---------------------------------------------------------------- node GEMM, LDS-staged weights
// Block = (node, nc[, row-half]); 4 waves. Weight slice [64 out-rows][128 k]
// converted fp32->bf16 once into LDS (padded stride 136 shorts -> 2-way max
// bank aliasing on ds_read_b128). Each wave computes MTPW*16 rows x 64 cols:
// per k0-step: MTPW global af loads + 4 LDS bq reads -> MTPW*4 MFMAs.
template <int MTPW>
__global__ __launch_bounds__(256) void k_gemm64(const bf16* __restrict__ A,
                                                const float* __restrict__ W,
                                                const float* __restrict__ bias,
                                                bf16* __restrict__ out, int nout,
                                                int astride, size_t woff, int wns,
                                                size_t boff, int bns, int relu,
                                                int nc_count) {
  __shared__ short WS[64 * 136];  // 17 KB
  const int RSPLIT = 4 / MTPW;
  int per_node = nc_count * RSPLIT;
  int node = blockIdx.x / per_node;
  int rem = blockIdx.x - node * per_node;
  int nc = rem / RSPLIT;
  int rh = rem - nc * RSPLIT;
  int tid = threadIdx.x;

  const float4* w4 = (const float4*)(W + woff + (size_t)node * (size_t)wns +
                                     (size_t)nc * 64 * DD);
  for (int i = tid; i < 2048; i += 256) {
    float4 v = w4[i];
    int row = i >> 5, k = (i & 31) << 2;
    short4a p = {bfs(v.x), bfs(v.y), bfs(v.z), bfs(v.w)};
    *(short4a*)&WS[row * 136 + k] = p;
  }
  __syncthreads();

  int w = tid >> 6, lane = tid & 63, r = lane & 15, quad = lane >> 4;
  int base_row = rh * 128 + w * (MTPW * 16);

  const bf16* arow[MTPW];
#pragma unroll
  for (int mt = 0; mt < MTPW; mt++)
    arow[mt] = A + ((size_t)node * BB + base_row + mt * 16 + r) * (size_t)astride + quad * 8;

  floatx4 acc[MTPW][4];
  floatx4 z = {0.f, 0.f, 0.f, 0.f};
#pragma unroll
  for (int mt = 0; mt < MTPW; mt++)
#pragma unroll
    for (int s = 0; s < 4; s++) acc[mt][s] = z;

#pragma unroll
  for (int k0 = 0; k0 < DD; k0 += 32) {
    short8 bq[4];
#pragma unroll
    for (int s = 0; s < 4; s++)
      bq[s] = *(const short8*)&WS[(s * 16 + r) * 136 + quad * 8 + k0];
#pragma unroll
    for (int mt = 0; mt < MTPW; mt++) {
      short8 af = *(const short8*)(arow[mt] + k0);
#pragma unroll
      for (int s = 0; s < 4; s++)
        acc[mt][s] = __builtin_amdgcn_mfma_f32_16x16x32_bf16(af, bq[s], acc[mt][s], 0, 0, 0);
    }
  }

  const float* bp = bias + boff + (size_t)node * (size_t)bns + nc * 64;
#pragma unroll
  for (int s = 0; s < 4; s++) {
    float bv = bp[s * 16 + r];
#pragma unroll
    for (int mt = 0; mt < MTPW; mt++) {
#pragma unroll
      for (int i = 0; i < 4; i++) {
        float v = acc[mt][s][i] + bv;
        if (relu) v = v > 0.f ? v : 0.f;
        int row = base_row + mt * 16 + quad * 4 + i;
        out[((size_t)node * BB + row) * (size_t)nout + nc * 64 + s * 16 + r] = (bf16)v;
      }
    }
  }
}

// ---------------------------------------------------------------- GEMM + residual + LN, all-register LN
// Block = (node, bt); full [128][128] weight in LDS (bf16, stride 136). Each
// wave computes 16 rows x 128 cols (acc[8]) so every output row lives in one
// wave: LN = in-register sums + shfl_xor over the 16 r-lanes. No Sm bounce.
__global__ __launch_bounds__(256) void k_lngemm(const bf16* __restrict__ A, int astride,
                                                const float* __restrict__ W,
                                                const float* __restrict__ bias,
                                                bf16* __restrict__ X,
                                                const float* __restrict__ g,
                                                const float* __restrict__ be,
                                                size_t woff, int wns, size_t boff,
                                                int bns, int gstride) {
  __shared__ short WS[128 * 136];  // 34 KB
  int node = blockIdx.x >> 2, bt = blockIdx.x & 3;
  int tid = threadIdx.x;

  const float4* w4 = (const float4*)(W + woff + (size_t)node * (size_t)wns);
  for (int i = tid; i < 4096; i += 256) {
    float4 v = w4[i];
    int row = i >> 5, k = (i & 31) << 2;
    short4a p = {bfs(v.x), bfs(v.y), bfs(v.z), bfs(v.w)};
    *(short4a*)&WS[row * 136 + k] = p;
  }
  __syncthreads();

  int w = tid >> 6, lane = tid & 63, r = lane & 15, quad = lane >> 4;
  int row0 = bt * 64 + w * 16;
  const bf16* arow = A + ((size_t)node * BB + row0 + r) * (size_t)astride + quad * 8;

  floatx4 acc[8];
  floatx4 z = {0.f, 0.f, 0.f, 0.f};
#pragma unroll
  for (int s = 0; s < 8; s++) acc[s] = z;

#pragma unroll
  for (int k0 = 0; k0 < DD; k0 += 32) {
    short8 af = *(const short8*)(arow + k0);
#pragma unroll
    for (int s = 0; s < 8; s++) {
      short8 bq = *(const short8*)&WS[(s * 16 + r) * 136 + quad * 8 + k0];
      acc[s] = __builtin_amdgcn_mfma_f32_16x16x32_bf16(af, bq, acc[s], 0, 0, 0);
    }
  }

  const float* bp = bias + boff + (size_t)node * (size_t)bns;
  float bv[8];
#pragma unroll
  for (int s = 0; s < 8; s++) bv[s] = bp[s * 16 + r];
  const float* gp = g + boff + (size_t)node * gstride;
  const float* bep = be + boff + (size_t)node * gstride;
  size_t xrow0 = (size_t)node * BB + row0;

#pragma unroll
  for (int i = 0; i < 4; i++) {
    size_t xb = (xrow0 + quad * 4 + i) * DD;
    float vv[8];
    float sum = 0.f;
#pragma unroll
    for (int s = 0; s < 8; s++) {
      vv[s] = acc[s][i] + bv[s] + (float)X[xb + s * 16 + r];
      sum += vv[s];
    }
    sum += __shfl_xor(sum, 1);
    sum += __shfl_xor(sum, 2);
    sum += __shfl_xor(sum, 4);
    sum += __shfl_xor(sum, 8);
    float mean = sum * (1.0f / 128.0f);
    float vs = 0.f;
#pragma unroll
    for (int s = 0; s < 8; s++) {
      float c = vv[s] - mean;
      vs += c * c;
    }
    vs += __shfl_xor(vs, 1);
    vs += __shfl_xor(vs, 2);
    vs += __shfl_xor(vs, 4);
    vs += __shfl_xor(vs, 8);
    float inv = rsqrtf(vs * (1.0f / 128.0f) + 1e-5f);
#pragma unroll
    for (int s = 0; s < 8; s++)
      X[xb + s * 16 + r] = (bf16)((vv[s] - mean) * inv * gp[s * 16 + r] + bep[s * 16 + r]);
  }
}

// ---------------------------------------------------------------- MFMA attention (in-place, Q slot)
__global__ __launch_bounds__(256) void k_attn(bf16* __restrict__ QKV) {
  __shared__ short VT[32 * 264];  // V^T [d][key], padded row stride 264 (16.9 KB)
  __shared__ short Pw[4 * 2560];  // per-wave P / O scratch, [16 rows][40] per qt (10.2 KB)
  int node = blockIdx.x >> 2, h = blockIdx.x & 3;
  int tid = threadIdx.x;
  int wave = tid >> 6, lane = tid & 63, quad = lane >> 4, l15 = lane & 15;
  short* sbase = (short*)(QKV + (size_t)node * BB * 384);

  // stage V^T: VT[d][key] = V[key][d]
  for (int i = tid; i < 4096; i += 256) {
    int key = i >> 4, dp = (i & 15) << 1;
    int two = *(const int*)(sbase + (size_t)key * 384 + 256 + h * 32 + dp);
    VT[dp * 264 + key] = (short)(two & 0xffff);
    VT[(dp + 1) * 264 + key] = (short)(((unsigned)two) >> 16);
  }

  // Q B-frags for this wave's 64 queries (read before any Q-slot write)
  int q0 = wave * 64;
  short8 qf[4];
#pragma unroll
  for (int qt = 0; qt < 4; qt++)
    qf[qt] = *(const short8*)(sbase + (size_t)(q0 + qt * 16 + l15) * 384 + h * 32 + quad * 8);

  __syncthreads();  // VT ready

  floatx4 zz = {0.f, 0.f, 0.f, 0.f};
  floatx4 acc[2][4];
#pragma unroll
  for (int dt = 0; dt < 2; dt++)
#pragma unroll
    for (int qt = 0; qt < 4; qt++) acc[dt][qt] = zz;
  float lp[4] = {0.f, 0.f, 0.f, 0.f};
  const float scale = 0.17677669529663689f;  // 1/sqrt(32)
  short* mypw = &Pw[wave * 2560];

  for (int g = 0; g < 8; g++) {
#pragma unroll
    for (int sub = 0; sub < 2; sub++) {
      int kt = g * 2 + sub;
      short8 kf = *(const short8*)(sbase + (size_t)(kt * 16 + l15) * 384 + 128 + h * 32 + quad * 8);
#pragma unroll
      for (int qt = 0; qt < 4; qt++) {
        floatx4 st = __builtin_amdgcn_mfma_f32_16x16x32_bf16(kf, qf[qt], zz, 0, 0, 0);
        float e0 = __expf(st[0] * scale);
        float e1 = __expf(st[1] * scale);
        float e2 = __expf(st[2] * scale);
        float e3 = __expf(st[3] * scale);
        lp[qt] += (e0 + e1) + (e2 + e3);
        short4a p = {bfs(e0), bfs(e1), bfs(e2), bfs(e3)};
        *(short4a*)(mypw + qt * 640 + l15 * 40 + sub * 16 + quad * 4) = p;
      }
    }
    short8 vf0 = *(const short8*)(&VT[l15 * 264 + g * 32 + quad * 8]);
    short8 vf1 = *(const short8*)(&VT[(16 + l15) * 264 + g * 32 + quad * 8]);
#pragma unroll
    for (int qt = 0; qt < 4; qt++) {
      short8 pf = *(const short8*)(mypw + qt * 640 + l15 * 40 + quad * 8);
      acc[0][qt] = __builtin_amdgcn_mfma_f32_16x16x32_bf16(vf0, pf, acc[0][qt], 0, 0, 0);
      acc[1][qt] = __builtin_amdgcn_mfma_f32_16x16x32_bf16(vf1, pf, acc[1][qt], 0, 0, 0);
    }
  }

  float inv[4];
#pragma unroll
  for (int qt = 0; qt < 4; qt++) {
    float lq = lp[qt];
    lq += __shfl_xor(lq, 16);
    lq += __shfl_xor(lq, 32);
    inv[qt] = 1.0f / lq;
  }

#pragma unroll
  for (int qt = 0; qt < 4; qt++)
#pragma unroll
    for (int dt = 0; dt < 2; dt++)
#pragma unroll
      for (int i = 0; i < 4; i++)
        mypw[(qt * 16 + l15) * 40 + dt * 16 + quad * 4 + i] = bfs(acc[dt][qt][i] * inv[qt]);

#pragma unroll
  for (int r = 0; r < 4; r++) {
    int chunk = r * 64 + lane;
    int query = chunk >> 2, d8 = (chunk & 3) * 8;
    short8 o = *(const short8*)(mypw + query * 40 + d8);
    *(short8*)(sbase + (size_t)(q0 + query) * 384 + h * 32 + d8) = o;
  }
}

// ---------------------------------------------------------------- fold GAT/pred/fc into 4 row-projection vectors
// NOTE: launched AFTER the layer loop — W4/C4 live inside the (then-dead) QKV region.
__global__ __launch_bounds__(256) void k_prep(const float* __restrict__ gatW,
                                              const float* __restrict__ attS,
                                              const float* __restrict__ attD,
                                              const float* __restrict__ predW,
                                              const float* __restrict__ fcW,
                                              const float* __restrict__ fcb,
                                              float* __restrict__ W4,
                                              float* __restrict__ C4) {
  __shared__ float U[4][64];
  int t = threadIdx.x;
  int tt = t >> 6, f = t & 63;
  float u = 0.f;
  if (tt == 0) {
    for (int g = 0; g < 64; g++) u += gatW[g * 64 + f] * attS[g];
  } else if (tt == 1) {
    for (int g = 0; g < 64; g++) u += gatW[g * 64 + f] * attD[g];
  } else if (tt == 2) {
    for (int g = 0; g < 64; g++) u += gatW[g * 64 + f] * predW[g];
  } else {
    for (int g = 0; g < 64; g++) u += gatW[g * 64 + f] * predW[64 + g];
  }
  U[tt][f] = u;
  __syncthreads();
  for (int idx = t; idx < 512; idx += 256) {
    int v = idx >> 7, d = idx & 127;
    float w = 0.f;
#pragma unroll
    for (int ff = 0; ff < 64; ff++) w += fcW[ff * 128 + d] * U[v][ff];
    W4[v * 128 + d] = w;
  }
  if (t < 4) {
    float c = 0.f;
#pragma unroll
    for (int ff = 0; ff < 64; ff++) c += fcb[ff] * U[t][ff];
    C4[t] = c;
  }
}

// ---------------------------------------------------------------- per-row 4 dot products over X
__global__ __launch_bounds__(256) void k_rows(const bf16* __restrict__ X,
                                              const float* __restrict__ W4,
                                              const float* __restrict__ C4,
                                              float* __restrict__ AS,
                                              float* __restrict__ ADv,
                                              float* __restrict__ HW0,
                                              float* __restrict__ HW1) {
  __shared__ float Wl[512];
  int t = threadIdx.x;
  Wl[t] = W4[t];
  Wl[t + 256] = W4[t + 256];
  __syncthreads();
  int wave = t >> 6, lane = t & 63;
  int rrow = lane >> 3, sub = lane & 7;
  int row = blockIdx.x * 32 + wave * 8 + rrow;
  const short* xp = (const short*)(X + (size_t)row * DD) + sub * 16;
  short8 a = *(const short8*)xp;
  short8 b = *(const short8*)(xp + 8);
  float a0 = 0.f, a1 = 0.f, a2 = 0.f, a3 = 0.f;
#pragma unroll
  for (int j = 0; j < 8; j++) {
    float xf = b2f(a[j]);
    int col = sub * 16 + j;
    a0 += xf * Wl[col];
    a1 += xf * Wl[128 + col];
    a2 += xf * Wl[256 + col];
    a3 += xf * Wl[384 + col];
  }
#pragma unroll
  for (int j = 0; j < 8; j++) {
    float xf = b2f(b[j]);
    int col = sub * 16 + 8 + j;
    a0 += xf * Wl[col];
    a1 += xf * Wl[128 + col];
    a2 += xf * Wl[256 + col];
    a3 += xf * Wl[384 + col];
  }
#pragma unroll
  for (int off = 1; off < 8; off <<= 1) {
    a0 += __shfl_xor(a0, off);
    a1 += __shfl_xor(a1, off);
    a2 += __shfl_xor(a2, off);
    a3 += __shfl_xor(a3, off);
  }
  if (sub == 0) {
    AS[row] = a0 + C4[0];
    ADv[row] = a1 + C4[1];
    HW0[row] = a2 + C4[2];
    HW1[row] = a3 + C4[3];
  }
}

// ---------------------------------------------------------------- zero
__global__ __launch_bounds__(256) void k_zero(float4* __restrict__ p, int n4) {
  int i = blockIdx.x * 256 + threadIdx.x;
  if (i < n4) p[i] = make_float4(0.f, 0.f, 0.f, 0.f);
}

// ---------------------------------------------------------------- edges -> 3 scalar accumulators
__global__ __launch_bounds__(256) void k_edge(const int* __restrict__ EI,
                                              const float* __restrict__ AS,
                                              const float* __restrict__ ADv,
                                              const float* __restrict__ HW0,
                                              const float* __restrict__ HW1,
                                              float* __restrict__ NUM0,
                                              float* __restrict__ NUM1,
                                              float* __restrict__ DEN) {
  int tid = blockIdx.x * 256 + threadIdx.x;
  if (tid >= BB * (NE + NN)) return;
  int b = tid / (NE + NN);
  int e = tid - b * (NE + NN);
  int s, d;
  if (e < NE) {
    s = EI[e];
    d = EI[NE + e];
  } else {
    s = d = e - NE;  // self loop
  }
  int js = b * NN + s, jd = b * NN + d;
  float ev = AS[js] + ADv[jd];
  float lr = ev > 0.f ? ev : 0.2f * ev;
  float w = __expf(lr);
  atomicAdd(&NUM0[jd], w * HW0[js]);
  atomicAdd(&NUM1[jd], w * HW1[js]);
  atomicAdd(&DEN[jd], w);
}

// ---------------------------------------------------------------- finalize
__global__ __launch_bounds__(256) void k_fin(const float* __restrict__ NUM0,
                                             const float* __restrict__ NUM1,
                                             const float* __restrict__ DEN,
                                             const float* __restrict__ gatB,
                                             const float* __restrict__ predW,
                                             const float* __restrict__ predB,
                                             float* __restrict__ OUT) {
  int tid = blockIdx.x * 256 + threadIdx.x;
  if (tid >= BB * NN) return;
  float c0 = predB[0], c1 = predB[1];
#pragma unroll
  for (int f = 0; f < 64; f++) {
    float gb = gatB[f];
    c0 += gb * predW[f];
    c1 += gb * predW[64 + f];
  }
  float inv = 1.0f / (DEN[tid] + 1e-16f);
  OUT[2 * tid] = NUM0[tid] * inv + c0;
  OUT[2 * tid + 1] = NUM1[tid] * inv + c1;
}

// ================================================================ launch
extern "C" void kernel_launch(void* const* d_in, const int* in_sizes, int n_in,
                              void* d_out, int out_size, void* d_ws, size_t ws_size,
                              hipStream_t stream) {
  const float* x = (const float*)d_in[0];
  const int* ei = (const int*)d_in[1];
  const float* Wqkv = (const float*)d_in[2];
  const float* bqkv = (const float*)d_in[3];
  const float* Wo = (const float*)d_in[4];
  const float* bo = (const float*)d_in[5];
  const float* g1 = (const float*)d_in[6];
  const float* be1 = (const float*)d_in[7];
  const float* fW1 = (const float*)d_in[8];
  const float* fb1 = (const float*)d_in[9];
  const float* fW2 = (const float*)d_in[10];
  const float* fb2 = (const float*)d_in[11];
  const float* g2 = (const float*)d_in[12];
  const float* be2 = (const float*)d_in[13];
  const float* fcW = (const float*)d_in[14];
  const float* fcb = (const float*)d_in[15];
  const float* gatW = (const float*)d_in[16];
  const float* attS = (const float*)d_in[17];
  const float* attD = (const float*)d_in[18];
  const float* gatB = (const float*)d_in[19];
  const float* predW = (const float*)d_in[20];
  const float* predB = (const float*)d_in[21];

  const size_t NEED = 52428800;
  if (ws_size < NEED) return;  // signature: absmax == max|ref|

  char* ws = (char*)d_ws;
  bf16* X = (bf16*)(ws);                  // [N][B][128]   0 .. 13,107,200
  bf16* QKV = (bf16*)(ws + 13107200);     // [N][B][384]  .. 52,428,800 (reused as H1)
  float* W4 = (float*)(ws + 40960000);    // [4][128]  (written AFTER loop; QKV dead)
  float* C4 = (float*)(ws + 40962048);    // [4]
  float* AS = (float*)(ws + 47513600);    // [51200]
  float* ADv = (float*)(ws + 47718400);   // [51200]
  float* HW0 = (float*)(ws + 47923200);   // [51200]
  float* HW1 = (float*)(ws + 48128000);   // [51200]
  float* NUM0 = (float*)(ws + 48332800);  // [51200]
  float* NUM1 = (float*)(ws + 48537600);  // [51200]
  float* DEN = (float*)(ws + 48742400);   // [51200]

  k_transpose<<<25600, 256, 0, stream>>>(x, X);

  for (int l = 0; l < LL; l++) {
    size_t w3o = (size_t)l * 384 * DD, b3o = (size_t)l * 384;
    size_t wso = (size_t)l * DD * DD, bso = (size_t)l * DD;
    k_gemm64<4><<<6 * NN, 256, 0, stream>>>(X, Wqkv, bqkv, QKV, 384, DD,
                                            w3o, LL * 384 * DD, b3o, LL * 384, 0, 6);
    k_attn<<<NN * 4, 256, 0, stream>>>(QKV);
    k_lngemm<<<4 * NN, 256, 0, stream>>>(QKV, 384, Wo, bo, X, g1, be1,
                                         wso, LL * DD * DD, bso, LL * DD, LL * DD);
    k_gemm64<2><<<4 * NN, 256, 0, stream>>>(X, fW1, fb1, QKV, 128, DD,
                                            wso, LL * DD * DD, bso, LL * DD, 1, 2);
    k_lngemm<<<4 * NN, 256, 0, stream>>>(QKV, 128, fW2, fb2, X, g2, be2,
                                         wso, LL * DD * DD, bso, LL * DD, LL * DD);
  }

  // QKV dead from here on: W4/C4 (inside the old QKV region) are now safe.
  k_prep<<<1, 256, 0, stream>>>(gatW, attS, attD, predW, fcW, fcb, W4, C4);
  k_rows<<<1600, 256, 0, stream>>>(X, W4, C4, AS, ADv, HW0, HW1);
  k_zero<<<150, 256, 0, stream>>>((float4*)NUM0, 38400);
  k_edge<<<1800, 256, 0, stream>>>(ei, AS, ADv, HW0, HW1, NUM0, NUM1, DEN);
  k_fin<<<200, 256, 0, stream>>>(NUM0, NUM1, DEN, gatB, predW, predB, (float*)d_out);
}

// Round 4
// 506.733 us; speedup vs baseline: 1.5019x; 1.0563x over previous
//
#include <hip/hip_runtime.h>
#include <hip/hip_bf16.h>

#define NN 200   // nodes
#define BB 256   // batch == attention sequence length
#define DD 128   // d_model == seq
#define DH 32    // head dim
#define NE 1600  // edges
#define LL 2     // layers

typedef short short8 __attribute__((ext_vector_type(8)));
typedef short short4a __attribute__((ext_vector_type(4)));
typedef float floatx4 __attribute__((ext_vector_type(4)));
using bf16 = __hip_bfloat16;

// Inputs fp32 (proven R1-R3); output fp32.

__device__ __forceinline__ short bfs(float x) {
  bf16 h = __float2bfloat16(x);
  return *(short*)&h;
}
__device__ __forceinline__ float b2f(short s) {
  union { unsigned u; float f; } cv;
  cv.u = ((unsigned)(unsigned short)s) << 16;
  return cv.f;
}

// XCD-clustered block decode: hardware round-robins wgid across the 8 XCDs
// (wg i -> XCD i&7). Putting all per_node blocks of a node on ONE XCD makes
// intra-node re-reads (X slice, weight matrix, QKV rows) hit that XCD's 4MB
// L2 instead of HBM. Requires grid == NN*per_node, NN%8==0.
__device__ __forceinline__ void swz_node(int bid, int per_node, int& node, int& rem) {
  int xcd = bid & 7;
  int slot = bid >> 3;
  int q = slot / per_node;
  node = xcd * (NN >> 3) + q;
  rem = slot - q * per_node;
}

// ---------------------------------------------------------------- transpose
__global__ __launch_bounds__(256) void k_transpose(const float* __restrict__ x,
                                                   bf16* __restrict__ X) {
  int tid = blockIdx.x * 256 + threadIdx.x;
  if (tid >= NN * BB * DD) return;
  int d = tid & (DD - 1);
  int rest = tid >> 7;
  int b = rest & (BB - 1);
  int node = rest >> 8;
  X[tid] = (bf16)x[((size_t)b * NN + node) * DD + d];
}

// ---------------------------------------------------------------- node GEMM, LDS-staged weights
// Block = (node, nc[, row-half]); 4 waves. Weight slice [64 out-rows][128 k]
// converted fp32->bf16 once into LDS (padded stride 136 shorts -> 2-way max
// bank aliasing on ds_read_b128). Each wave computes MTPW*16 rows x 64 cols.
template <int MTPW>
__global__ __launch_bounds__(256) void k_gemm64(const bf16* __restrict__ A,
                                                const float* __restrict__ W,
                                                const float* __restrict__ bias,
                                                bf16* __restrict__ out, int nout,
                                                int astride, size_t woff, int wns,
                                                size_t boff, int bns, int relu,
                                                int nc_count) {
  __shared__ short WS[64 * 136];  // 17 KB
  const int RSPLIT = 4 / MTPW;
  int per_node = nc_count * RSPLIT;
  int node, rem;
  swz_node(blockIdx.x, per_node, node, rem);
  int nc = rem / RSPLIT;
  int rh = rem - nc * RSPLIT;
  int tid = threadIdx.x;

  const float4* w4 = (const float4*)(W + woff + (size_t)node * (size_t)wns +
                                     (size_t)nc * 64 * DD);
  for (int i = tid; i < 2048; i += 256) {
    float4 v = w4[i];
    int row = i >> 5, k = (i & 31) << 2;
    short4a p = {bfs(v.x), bfs(v.y), bfs(v.z), bfs(v.w)};
    *(short4a*)&WS[row * 136 + k] = p;
  }
  __syncthreads();

  int w = tid >> 6, lane = tid & 63, r = lane & 15, quad = lane >> 4;
  int base_row = rh * 128 + w * (MTPW * 16);

  const bf16* arow[MTPW];
#pragma unroll
  for (int mt = 0; mt < MTPW; mt++)
    arow[mt] = A + ((size_t)node * BB + base_row + mt * 16 + r) * (size_t)astride + quad * 8;

  floatx4 acc[MTPW][4];
  floatx4 z = {0.f, 0.f, 0.f, 0.f};
#pragma unroll
  for (int mt = 0; mt < MTPW; mt++)
#pragma unroll
    for (int s = 0; s < 4; s++) acc[mt][s] = z;

#pragma unroll
  for (int k0 = 0; k0 < DD; k0 += 32) {
    short8 bq[4];
#pragma unroll
    for (int s = 0; s < 4; s++)
      bq[s] = *(const short8*)&WS[(s * 16 + r) * 136 + quad * 8 + k0];
#pragma unroll
    for (int mt = 0; mt < MTPW; mt++) {
      short8 af = *(const short8*)(arow[mt] + k0);
#pragma unroll
      for (int s = 0; s < 4; s++)
        acc[mt][s] = __builtin_amdgcn_mfma_f32_16x16x32_bf16(af, bq[s], acc[mt][s], 0, 0, 0);
    }
  }

  const float* bp = bias + boff + (size_t)node * (size_t)bns + nc * 64;
#pragma unroll
  for (int s = 0; s < 4; s++) {
    float bv = bp[s * 16 + r];
#pragma unroll
    for (int mt = 0; mt < MTPW; mt++) {
#pragma unroll
      for (int i = 0; i < 4; i++) {
        float v = acc[mt][s][i] + bv;
        if (relu) v = v > 0.f ? v : 0.f;
        int row = base_row + mt * 16 + quad * 4 + i;
        out[((size_t)node * BB + row) * (size_t)nout + nc * 64 + s * 16 + r] = (bf16)v;
      }
    }
  }
}

// ---------------------------------------------------------------- GEMM + residual + LN, all-register LN
// Block = (node, bt); full [128][128] weight in LDS (bf16, stride 136). Each
// wave computes 16 rows x 128 cols (acc[8]) so every output row lives in one
// wave: LN = in-register sums + shfl_xor over the 16 r-lanes. No Sm bounce.
__global__ __launch_bounds__(256) void k_lngemm(const bf16* __restrict__ A, int astride,
                                                const float* __restrict__ W,
                                                const float* __restrict__ bias,
                                                bf16* __restrict__ X,
                                                const float* __restrict__ g,
                                                const float* __restrict__ be,
                                                size_t woff, int wns, size_t boff,
                                                int bns, int gstride) {
  __shared__ short WS[128 * 136];  // 34 KB
  int node, bt;
  swz_node(blockIdx.x, 4, node, bt);
  int tid = threadIdx.x;

  const float4* w4 = (const float4*)(W + woff + (size_t)node * (size_t)wns);
  for (int i = tid; i < 4096; i += 256) {
    float4 v = w4[i];
    int row = i >> 5, k = (i & 31) << 2;
    short4a p = {bfs(v.x), bfs(v.y), bfs(v.z), bfs(v.w)};
    *(short4a*)&WS[row * 136 + k] = p;
  }
  __syncthreads();

  int w = tid >> 6, lane = tid & 63, r = lane & 15, quad = lane >> 4;
  int row0 = bt * 64 + w * 16;
  const bf16* arow = A + ((size_t)node * BB + row0 + r) * (size_t)astride + quad * 8;

  floatx4 acc[8];
  floatx4 z = {0.f, 0.f, 0.f, 0.f};
#pragma unroll
  for (int s = 0; s < 8; s++) acc[s] = z;

#pragma unroll
  for (int k0 = 0; k0 < DD; k0 += 32) {
    short8 af = *(const short8*)(arow + k0);
#pragma unroll
    for (int s = 0; s < 8; s++) {
      short8 bq = *(const short8*)&WS[(s * 16 + r) * 136 + quad * 8 + k0];
      acc[s] = __builtin_amdgcn_mfma_f32_16x16x32_bf16(af, bq, acc[s], 0, 0, 0);
    }
  }

  const float* bp = bias + boff + (size_t)node * (size_t)bns;
  float bv[8];
#pragma unroll
  for (int s = 0; s < 8; s++) bv[s] = bp[s * 16 + r];
  const float* gp = g + boff + (size_t)node * gstride;
  const float* bep = be + boff + (size_t)node * gstride;
  size_t xrow0 = (size_t)node * BB + row0;

#pragma unroll
  for (int i = 0; i < 4; i++) {
    size_t xb = (xrow0 + quad * 4 + i) * DD;
    float vv[8];
    float sum = 0.f;
#pragma unroll
    for (int s = 0; s < 8; s++) {
      vv[s] = acc[s][i] + bv[s] + (float)X[xb + s * 16 + r];
      sum += vv[s];
    }
    sum += __shfl_xor(sum, 1);
    sum += __shfl_xor(sum, 2);
    sum += __shfl_xor(sum, 4);
    sum += __shfl_xor(sum, 8);
    float mean = sum * (1.0f / 128.0f);
    float vs = 0.f;
#pragma unroll
    for (int s = 0; s < 8; s++) {
      float c = vv[s] - mean;
      vs += c * c;
    }
    vs += __shfl_xor(vs, 1);
    vs += __shfl_xor(vs, 2);
    vs += __shfl_xor(vs, 4);
    vs += __shfl_xor(vs, 8);
    float inv = rsqrtf(vs * (1.0f / 128.0f) + 1e-5f);
#pragma unroll
    for (int s = 0; s < 8; s++)
      X[xb + s * 16 + r] = (bf16)((vv[s] - mean) * inv * gp[s * 16 + r] + bep[s * 16 + r]);
  }
}

// ---------------------------------------------------------------- MFMA attention (in-place, Q slot)
__global__ __launch_bounds__(256) void k_attn(bf16* __restrict__ QKV) {
  __shared__ short VT[32 * 264];  // V^T [d][key], padded row stride 264 (16.9 KB)
  __shared__ short Pw[4 * 2560];  // per-wave P / O scratch, [16 rows][40] per qt (10.2 KB)
  int node, h;
  swz_node(blockIdx.x, 4, node, h);
  int tid = threadIdx.x;
  int wave = tid >> 6, lane = tid & 63, quad = lane >> 4, l15 = lane & 15;
  short* sbase = (short*)(QKV + (size_t)node * BB * 384);

  // stage V^T: VT[d][key] = V[key][d]
  for (int i = tid; i < 4096; i += 256) {
    int key = i >> 4, dp = (i & 15) << 1;
    int two = *(const int*)(sbase + (size_t)key * 384 + 256 + h * 32 + dp);
    VT[dp * 264 + key] = (short)(two & 0xffff);
    VT[(dp + 1) * 264 + key] = (short)(((unsigned)two) >> 16);
  }

  // Q B-frags for this wave's 64 queries (read before any Q-slot write)
  int q0 = wave * 64;
  short8 qf[4];
#pragma unroll
  for (int qt = 0; qt < 4; qt++)
    qf[qt] = *(const short8*)(sbase + (size_t)(q0 + qt * 16 + l15) * 384 + h * 32 + quad * 8);

  __syncthreads();  // VT ready

  floatx4 zz = {0.f, 0.f, 0.f, 0.f};
  floatx4 acc[2][4];
#pragma unroll
  for (int dt = 0; dt < 2; dt++)
#pragma unroll
    for (int qt = 0; qt < 4; qt++) acc[dt][qt] = zz;
  float lp[4] = {0.f, 0.f, 0.f, 0.f};
  const float scale = 0.17677669529663689f;  // 1/sqrt(32)
  short* mypw = &Pw[wave * 2560];

  for (int g = 0; g < 8; g++) {
#pragma unroll
    for (int sub = 0; sub < 2; sub++) {
      int kt = g * 2 + sub;
      short8 kf = *(const short8*)(sbase + (size_t)(kt * 16 + l15) * 384 + 128 + h * 32 + quad * 8);
#pragma unroll
      for (int qt = 0; qt < 4; qt++) {
        floatx4 st = __builtin_amdgcn_mfma_f32_16x16x32_bf16(kf, qf[qt], zz, 0, 0, 0);
        float e0 = __expf(st[0] * scale);
        float e1 = __expf(st[1] * scale);
        float e2 = __expf(st[2] * scale);
        float e3 = __expf(st[3] * scale);
        lp[qt] += (e0 + e1) + (e2 + e3);
        short4a p = {bfs(e0), bfs(e1), bfs(e2), bfs(e3)};
        *(short4a*)(mypw + qt * 640 + l15 * 40 + sub * 16 + quad * 4) = p;
      }
    }
    short8 vf0 = *(const short8*)(&VT[l15 * 264 + g * 32 + quad * 8]);
    short8 vf1 = *(const short8*)(&VT[(16 + l15) * 264 + g * 32 + quad * 8]);
#pragma unroll
    for (int qt = 0; qt < 4; qt++) {
      short8 pf = *(const short8*)(mypw + qt * 640 + l15 * 40 + quad * 8);
      acc[0][qt] = __builtin_amdgcn_mfma_f32_16x16x32_bf16(vf0, pf, acc[0][qt], 0, 0, 0);
      acc[1][qt] = __builtin_amdgcn_mfma_f32_16x16x32_bf16(vf1, pf, acc[1][qt], 0, 0, 0);
    }
  }

  float inv[4];
#pragma unroll
  for (int qt = 0; qt < 4; qt++) {
    float lq = lp[qt];
    lq += __shfl_xor(lq, 16);
    lq += __shfl_xor(lq, 32);
    inv[qt] = 1.0f / lq;
  }

#pragma unroll
  for (int qt = 0; qt < 4; qt++)
#pragma unroll
    for (int dt = 0; dt < 2; dt++)
#pragma unroll
      for (int i = 0; i < 4; i++)
        mypw[(qt * 16 + l15) * 40 + dt * 16 + quad * 4 + i] = bfs(acc[dt][qt][i] * inv[qt]);

#pragma unroll
  for (int r = 0; r < 4; r++) {
    int chunk = r * 64 + lane;
    int query = chunk >> 2, d8 = (chunk & 3) * 8;
    short8 o = *(const short8*)(mypw + query * 40 + d8);
    *(short8*)(sbase + (size_t)(q0 + query) * 384 + h * 32 + d8) = o;
  }
}

// ---------------------------------------------------------------- fold GAT/pred/fc into 4 row-projection vectors
// NOTE: launched AFTER the layer loop — W4/C4 live inside the (then-dead) QKV region.
__global__ __launch_bounds__(256) void k_prep(const float* __restrict__ gatW,
                                              const float* __restrict__ attS,
                                              const float* __restrict__ attD,
                                              const float* __restrict__ predW,
                                              const float* __restrict__ fcW,
                                              const float* __restrict__ fcb,
                                              float* __restrict__ W4,
                                              float* __restrict__ C4) {
  __shared__ float U[4][64];
  int t = threadIdx.x;
  int tt = t >> 6, f = t & 63;
  float u = 0.f;
  if (tt == 0) {
    for (int g = 0; g < 64; g++) u += gatW[g * 64 + f] * attS[g];
  } else if (tt == 1) {
    for (int g = 0; g < 64; g++) u += gatW[g * 64 + f] * attD[g];
  } else if (tt == 2) {
    for (int g = 0; g < 64; g++) u += gatW[g * 64 + f] * predW[g];
  } else {
    for (int g = 0; g < 64; g++) u += gatW[g * 64 + f] * predW[64 + g];
  }
  U[tt][f] = u;
  __syncthreads();
  for (int idx = t; idx < 512; idx += 256) {
    int v = idx >> 7, d = idx & 127;
    float w = 0.f;
#pragma unroll
    for (int ff = 0; ff < 64; ff++) w += fcW[ff * 128 + d] * U[v][ff];
    W4[v * 128 + d] = w;
  }
  if (t < 4) {
    float c = 0.f;
#pragma unroll
    for (int ff = 0; ff < 64; ff++) c += fcb[ff] * U[t][ff];
    C4[t] = c;
  }
}

// ---------------------------------------------------------------- per-row 4 dot products over X
__global__ __launch_bounds__(256) void k_rows(const bf16* __restrict__ X,
                                              const float* __restrict__ W4,
                                              const float* __restrict__ C4,
                                              float* __restrict__ AS,
                                              float* __restrict__ ADv,
                                              float* __restrict__ HW0,
                                              float* __restrict__ HW1) {
  __shared__ float Wl[512];
  int t = threadIdx.x;
  Wl[t] = W4[t];
  Wl[t + 256] = W4[t + 256];
  __syncthreads();
  int wave = t >> 6, lane = t & 63;
  int rrow = lane >> 3, sub = lane & 7;
  int row = blockIdx.x * 32 + wave * 8 + rrow;
  const short* xp = (const short*)(X + (size_t)row * DD) + sub * 16;
  short8 a = *(const short8*)xp;
  short8 b = *(const short8*)(xp + 8);
  float a0 = 0.f, a1 = 0.f, a2 = 0.f, a3 = 0.f;
#pragma unroll
  for (int j = 0; j < 8; j++) {
    float xf = b2f(a[j]);
    int col = sub * 16 + j;
    a0 += xf * Wl[col];
    a1 += xf * Wl[128 + col];
    a2 += xf * Wl[256 + col];
    a3 += xf * Wl[384 + col];
  }
#pragma unroll
  for (int j = 0; j < 8; j++) {
    float xf = b2f(b[j]);
    int col = sub * 16 + 8 + j;
    a0 += xf * Wl[col];
    a1 += xf * Wl[128 + col];
    a2 += xf * Wl[256 + col];
    a3 += xf * Wl[384 + col];
  }
#pragma unroll
  for (int off = 1; off < 8; off <<= 1) {
    a0 += __shfl_xor(a0, off);
    a1 += __shfl_xor(a1, off);
    a2 += __shfl_xor(a2, off);
    a3 += __shfl_xor(a3, off);
  }
  if (sub == 0) {
    AS[row] = a0 + C4[0];
    ADv[row] = a1 + C4[1];
    HW0[row] = a2 + C4[2];
    HW1[row] = a3 + C4[3];
  }
}

// ---------------------------------------------------------------- zero
__global__ __launch_bounds__(256) void k_zero(float4* __restrict__ p, int n4) {
  int i = blockIdx.x * 256 + threadIdx.x;
  if (i < n4) p[i] = make_float4(0.f, 0.f, 0.f, 0.f);
}

// ---------------------------------------------------------------- edges -> 3 scalar accumulators
__global__ __launch_bounds__(256) void k_edge(const int* __restrict__ EI,
                                              const float* __restrict__ AS,
                                              const float* __restrict__ ADv,
                                              const float* __restrict__ HW0,
                                              const float* __restrict__ HW1,
                                              float* __restrict__ NUM0,
                                              float* __restrict__ NUM1,
                                              float* __restrict__ DEN) {
  int tid = blockIdx.x * 256 + threadIdx.x;
  if (tid >= BB * (NE + NN)) return;
  int b = tid / (NE + NN);
  int e = tid - b * (NE + NN);
  int s, d;
  if (e < NE) {
    s = EI[e];
    d = EI[NE + e];
  } else {
    s = d = e - NE;  // self loop
  }
  int js = b * NN + s, jd = b * NN + d;
  float ev = AS[js] + ADv[jd];
  float lr = ev > 0.f ? ev : 0.2f * ev;
  float w = __expf(lr);
  atomicAdd(&NUM0[jd], w * HW0[js]);
  atomicAdd(&NUM1[jd], w * HW1[js]);
  atomicAdd(&DEN[jd], w);
}

// ---------------------------------------------------------------- finalize
__global__ __launch_bounds__(256) void k_fin(const float* __restrict__ NUM0,
                                             const float* __restrict__ NUM1,
                                             const float* __restrict__ DEN,
                                             const float* __restrict__ gatB,
                                             const float* __restrict__ predW,
                                             const float* __restrict__ predB,
                                             float* __restrict__ OUT) {
  int tid = blockIdx.x * 256 + threadIdx.x;
  if (tid >= BB * NN) return;
  float c0 = predB[0], c1 = predB[1];
#pragma unroll
  for (int f = 0; f < 64; f++) {
    float gb = gatB[f];
    c0 += gb * predW[f];
    c1 += gb * predW[64 + f];
  }
  float inv = 1.0f / (DEN[tid] + 1e-16f);
  OUT[2 * tid] = NUM0[tid] * inv + c0;
  OUT[2 * tid + 1] = NUM1[tid] * inv + c1;
}

// ================================================================ launch
extern "C" void kernel_launch(void* const* d_in, const int* in_sizes, int n_in,
                              void* d_out, int out_size, void* d_ws, size_t ws_size,
                              hipStream_t stream) {
  const float* x = (const float*)d_in[0];
  const int* ei = (const int*)d_in[1];
  const float* Wqkv = (const float*)d_in[2];
  const float* bqkv = (const float*)d_in[3];
  const float* Wo = (const float*)d_in[4];
  const float* bo = (const float*)d_in[5];
  const float* g1 = (const float*)d_in[6];
  const float* be1 = (const float*)d_in[7];
  const float* fW1 = (const float*)d_in[8];
  const float* fb1 = (const float*)d_in[9];
  const float* fW2 = (const float*)d_in[10];
  const float* fb2 = (const float*)d_in[11];
  const float* g2 = (const float*)d_in[12];
  const float* be2 = (const float*)d_in[13];
  const float* fcW = (const float*)d_in[14];
  const float* fcb = (const float*)d_in[15];
  const float* gatW = (const float*)d_in[16];
  const float* attS = (const float*)d_in[17];
  const float* attD = (const float*)d_in[18];
  const float* gatB = (const float*)d_in[19];
  const float* predW = (const float*)d_in[20];
  const float* predB = (const float*)d_in[21];

  const size_t NEED = 52428800;
  if (ws_size < NEED) return;  // signature: absmax == max|ref|

  char* ws = (char*)d_ws;
  bf16* X = (bf16*)(ws);                  // [N][B][128]   0 .. 13,107,200
  bf16* QKV = (bf16*)(ws + 13107200);     // [N][B][384]  .. 52,428,800 (reused as H1)
  float* W4 = (float*)(ws + 40960000);    // [4][128]  (written AFTER loop; QKV dead)
  float* C4 = (float*)(ws + 40962048);    // [4]
  float* AS = (float*)(ws + 47513600);    // [51200]
  float* ADv = (float*)(ws + 47718400);   // [51200]
  float* HW0 = (float*)(ws + 47923200);   // [51200]
  float* HW1 = (float*)(ws + 48128000);   // [51200]
  float* NUM0 = (float*)(ws + 48332800);  // [51200]
  float* NUM1 = (float*)(ws + 48537600);  // [51200]
  float* DEN = (float*)(ws + 48742400);   // [51200]

  k_transpose<<<25600, 256, 0, stream>>>(x, X);

  for (int l = 0; l < LL; l++) {
    size_t w3o = (size_t)l * 384 * DD, b3o = (size_t)l * 384;
    size_t wso = (size_t)l * DD * DD, bso = (size_t)l * DD;
    k_gemm64<4><<<6 * NN, 256, 0, stream>>>(X, Wqkv, bqkv, QKV, 384, DD,
                                            w3o, LL * 384 * DD, b3o, LL * 384, 0, 6);
    k_attn<<<NN * 4, 256, 0, stream>>>(QKV);
    k_lngemm<<<4 * NN, 256, 0, stream>>>(QKV, 384, Wo, bo, X, g1, be1,
                                         wso, LL * DD * DD, bso, LL * DD, LL * DD);
    k_gemm64<2><<<4 * NN, 256, 0, stream>>>(X, fW1, fb1, QKV, 128, DD,
                                            wso, LL * DD * DD, bso, LL * DD, 1, 2);
    k_lngemm<<<4 * NN, 256, 0, stream>>>(QKV, 128, fW2, fb2, X, g2, be2,
                                         wso, LL * DD * DD, bso, LL * DD, LL * DD);
  }

  // QKV dead from here on: W4/C4 (inside the old QKV region) are now safe.
  k_prep<<<1, 256, 0, stream>>>(gatW, attS, attD, predW, fcW, fcb, W4, C4);
  k_rows<<<1600, 256, 0, stream>>>(X, W4, C4, AS, ADv, HW0, HW1);
  k_zero<<<150, 256, 0, stream>>>((float4*)NUM0, 38400);
  k_edge<<<1800, 256, 0, stream>>>(ei, AS, ADv, HW0, HW1, NUM0, NUM1, DEN);
  k_fin<<<200, 256, 0, stream>>>(NUM0, NUM1, DEN, gatB, predW, predB, (float*)d_out);
}

// Round 5
// 496.145 us; speedup vs baseline: 1.5339x; 1.0213x over previous
//
#include <hip/hip_runtime.h>
#include <hip/hip_bf16.h>

#define NN 200   // nodes
#define BB 256   // batch == attention sequence length
#define DD 128   // d_model == seq
#define DH 32    // head dim
#define NE 1600  // edges
#define LL 2     // layers

typedef short short8 __attribute__((ext_vector_type(8)));
typedef short short4a __attribute__((ext_vector_type(4)));
typedef float floatx4 __attribute__((ext_vector_type(4)));
using bf16 = __hip_bfloat16;

// Inputs fp32 (proven R1-R3); output fp32.

__device__ __forceinline__ short bfs(float x) {
  bf16 h = __float2bfloat16(x);
  return *(short*)&h;
}
__device__ __forceinline__ float b2f(short s) {
  union { unsigned u; float f; } cv;
  cv.u = ((unsigned)(unsigned short)s) << 16;
  return cv.f;
}

// XCD-clustered block decode: hardware round-robins wgid across the 8 XCDs
// (wg i -> XCD i&7). Putting all per_node blocks of a node on ONE XCD makes
// intra-node re-reads (X slice, weight matrix, QKV rows) hit that XCD's 4MB
// L2 instead of HBM (R4: FETCH 78->26MB). Requires grid == NN*per_node, NN%8==0.
__device__ __forceinline__ void swz_node(int bid, int per_node, int& node, int& rem) {
  int xcd = bid & 7;
  int slot = bid >> 3;
  int q = slot / per_node;
  node = xcd * (NN >> 3) + q;
  rem = slot - q * per_node;
}

// ---------------------------------------------------------------- transpose
__global__ __launch_bounds__(256) void k_transpose(const float* __restrict__ x,
                                                   bf16* __restrict__ X) {
  int tid = blockIdx.x * 256 + threadIdx.x;
  if (tid >= NN * BB * DD) return;
  int d = tid & (DD - 1);
  int rest = tid >> 7;
  int b = rest & (BB - 1);
  int node = rest >> 8;
  X[tid] = (bf16)x[((size_t)b * NN + node) * DD + d];
}

// ---------------------------------------------------------------- node GEMM, LDS-staged weights
// Block = (node, nc[, row-half]); 4 waves. Weight slice [64 out-rows][128 k]
// converted fp32->bf16 once into LDS (padded stride 136 shorts). Epilogue
// bounces each wave's 16x64 tile through (dead) WS -> coalesced short8 stores
// (R4: 64 scalar 2B stores/lane caused WRITE_SIZE 60MB vs 39MB ideal).
template <int MTPW>
__global__ __launch_bounds__(256) void k_gemm64(const bf16* __restrict__ A,
                                                const float* __restrict__ W,
                                                const float* __restrict__ bias,
                                                bf16* __restrict__ out, int nout,
                                                int astride, size_t woff, int wns,
                                                size_t boff, int bns, int relu,
                                                int nc_count) {
  __shared__ short WS[64 * 136];  // 17 KB
  const int RSPLIT = 4 / MTPW;
  int per_node = nc_count * RSPLIT;
  int node, rem;
  swz_node(blockIdx.x, per_node, node, rem);
  int nc = rem / RSPLIT;
  int rh = rem - nc * RSPLIT;
  int tid = threadIdx.x;

  const float4* w4 = (const float4*)(W + woff + (size_t)node * (size_t)wns +
                                     (size_t)nc * 64 * DD);
  for (int i = tid; i < 2048; i += 256) {
    float4 v = w4[i];
    int row = i >> 5, k = (i & 31) << 2;
    short4a p = {bfs(v.x), bfs(v.y), bfs(v.z), bfs(v.w)};
    *(short4a*)&WS[row * 136 + k] = p;
  }
  __syncthreads();

  int w = tid >> 6, lane = tid & 63, r = lane & 15, quad = lane >> 4;
  int base_row = rh * 128 + w * (MTPW * 16);

  const bf16* arow[MTPW];
#pragma unroll
  for (int mt = 0; mt < MTPW; mt++)
    arow[mt] = A + ((size_t)node * BB + base_row + mt * 16 + r) * (size_t)astride + quad * 8;

  floatx4 acc[MTPW][4];
  floatx4 z = {0.f, 0.f, 0.f, 0.f};
#pragma unroll
  for (int mt = 0; mt < MTPW; mt++)
#pragma unroll
    for (int s = 0; s < 4; s++) acc[mt][s] = z;

#pragma unroll
  for (int k0 = 0; k0 < DD; k0 += 32) {
    short8 bq[4];
#pragma unroll
    for (int s = 0; s < 4; s++)
      bq[s] = *(const short8*)&WS[(s * 16 + r) * 136 + quad * 8 + k0];
#pragma unroll
    for (int mt = 0; mt < MTPW; mt++) {
      short8 af = *(const short8*)(arow[mt] + k0);
#pragma unroll
      for (int s = 0; s < 4; s++)
        acc[mt][s] = __builtin_amdgcn_mfma_f32_16x16x32_bf16(af, bq[s], acc[mt][s], 0, 0, 0);
    }
  }

  const float* bp = bias + boff + (size_t)node * (size_t)bns + nc * 64;
  float bv[4];
#pragma unroll
  for (int s = 0; s < 4; s++) bv[s] = bp[s * 16 + r];

  __syncthreads();  // all waves finished reading WS weights; reuse as bounce
  short* mybw = &WS[w * 1088];  // per-wave [16][68]
  const size_t obase = (size_t)node * BB + base_row;
#pragma unroll
  for (int mt = 0; mt < MTPW; mt++) {
#pragma unroll
    for (int s = 0; s < 4; s++) {
#pragma unroll
      for (int i = 0; i < 4; i++) {
        float v = acc[mt][s][i] + bv[s];
        if (relu) v = v > 0.f ? v : 0.f;
        mybw[(quad * 4 + i) * 68 + s * 16 + r] = bfs(v);
      }
    }
    // wave-private region; per-wave LDS ordering makes reads see the writes,
    // and next mt's writes wait behind these reads (same array -> no reorder).
#pragma unroll
    for (int j = 0; j < 2; j++) {
      int chunk = j * 64 + lane;
      int rowr = chunk >> 3, c8 = chunk & 7;
      short8 o = *(const short8*)&mybw[rowr * 68 + c8 * 8];
      *(short8*)((short*)out + (obase + mt * 16 + rowr) * (size_t)nout + nc * 64 + c8 * 8) = o;
    }
  }
}

// ---------------------------------------------------------------- GEMM + residual + LN
// Full [128][128] weight in LDS (bf16, stride 136). Wave computes 16 rows x
// 128 cols. Epilogue: bounce fp32 acc+bias through BB4 (two 64-col halves) so
// each lane owns 32 CONTIGUOUS cols of one row -> coalesced short8 residual
// loads + stores; LN reduce = 2 shfl_xor over the 4-lane row group.
__global__ __launch_bounds__(256) void k_lngemm(const bf16* __restrict__ A, int astride,
                                                const float* __restrict__ W,
                                                const float* __restrict__ bias,
                                                bf16* __restrict__ X,
                                                const float* __restrict__ g,
                                                const float* __restrict__ be,
                                                size_t woff, int wns, size_t boff,
                                                int bns, int gstride) {
  __shared__ short WS[128 * 136];    // 34 KB
  __shared__ float BB4[4][16][68];   // 17 KB fp32 bounce, per wave
  int node, bt;
  swz_node(blockIdx.x, 4, node, bt);
  int tid = threadIdx.x;

  const float4* w4 = (const float4*)(W + woff + (size_t)node * (size_t)wns);
  for (int i = tid; i < 4096; i += 256) {
    float4 v = w4[i];
    int row = i >> 5, k = (i & 31) << 2;
    short4a p = {bfs(v.x), bfs(v.y), bfs(v.z), bfs(v.w)};
    *(short4a*)&WS[row * 136 + k] = p;
  }
  __syncthreads();

  int w = tid >> 6, lane = tid & 63, r = lane & 15, quad = lane >> 4;
  int row0 = bt * 64 + w * 16;
  const bf16* arow = A + ((size_t)node * BB + row0 + r) * (size_t)astride + quad * 8;

  floatx4 acc[8];
  floatx4 z = {0.f, 0.f, 0.f, 0.f};
#pragma unroll
  for (int s = 0; s < 8; s++) acc[s] = z;

#pragma unroll
  for (int k0 = 0; k0 < DD; k0 += 32) {
    short8 af = *(const short8*)(arow + k0);
#pragma unroll
    for (int s = 0; s < 8; s++) {
      short8 bq = *(const short8*)&WS[(s * 16 + r) * 136 + quad * 8 + k0];
      acc[s] = __builtin_amdgcn_mfma_f32_16x16x32_bf16(af, bq, acc[s], 0, 0, 0);
    }
  }

  const float* bp = bias + boff + (size_t)node * (size_t)bns;
  float bv[8];
#pragma unroll
  for (int s = 0; s < 8; s++) bv[s] = bp[s * 16 + r];

  int rrow = lane >> 2, cg = lane & 3;
  float vv[32];
  // half 0: cols 0..63 (s=0..3)
#pragma unroll
  for (int s = 0; s < 4; s++)
#pragma unroll
    for (int i = 0; i < 4; i++)
      BB4[w][quad * 4 + i][s * 16 + r] = acc[s][i] + bv[s];
  if (cg < 2) {
#pragma unroll
    for (int j = 0; j < 8; j++) {
      float4 t4 = *(const float4*)&BB4[w][rrow][(cg & 1) * 32 + j * 4];
      vv[j * 4 + 0] = t4.x; vv[j * 4 + 1] = t4.y;
      vv[j * 4 + 2] = t4.z; vv[j * 4 + 3] = t4.w;
    }
  }
  // half 1: cols 64..127 (s=4..7) — wave-private, in-order LDS => WAR safe
#pragma unroll
  for (int s = 0; s < 4; s++)
#pragma unroll
    for (int i = 0; i < 4; i++)
      BB4[w][quad * 4 + i][s * 16 + r] = acc[s + 4][i] + bv[s + 4];
  if (cg >= 2) {
#pragma unroll
    for (int j = 0; j < 8; j++) {
      float4 t4 = *(const float4*)&BB4[w][rrow][(cg & 1) * 32 + j * 4];
      vv[j * 4 + 0] = t4.x; vv[j * 4 + 1] = t4.y;
      vv[j * 4 + 2] = t4.z; vv[j * 4 + 3] = t4.w;
    }
  }

  // residual (coalesced short8), then LN over the 4-lane row group
  size_t xrow = ((size_t)node * BB + row0 + rrow) * DD + cg * 32;
  const short* xr = (const short*)X + xrow;
  float sum = 0.f;
#pragma unroll
  for (int c = 0; c < 4; c++) {
    short8 xs = *(const short8*)(xr + c * 8);
#pragma unroll
    for (int j = 0; j < 8; j++) {
      vv[c * 8 + j] += b2f(xs[j]);
      sum += vv[c * 8 + j];
    }
  }
  sum += __shfl_xor(sum, 1);
  sum += __shfl_xor(sum, 2);
  float mean = sum * (1.0f / 128.0f);
  float vs = 0.f;
#pragma unroll
  for (int j = 0; j < 32; j++) {
    float c = vv[j] - mean;
    vs += c * c;
  }
  vs += __shfl_xor(vs, 1);
  vs += __shfl_xor(vs, 2);
  float inv = rsqrtf(vs * (1.0f / 128.0f) + 1e-5f);

  const float* gp = g + boff + (size_t)node * gstride + cg * 32;
  const float* bep = be + boff + (size_t)node * gstride + cg * 32;
#pragma unroll
  for (int c = 0; c < 4; c++) {
    short8 os;
#pragma unroll
    for (int q2 = 0; q2 < 2; q2++) {
      float4 g4 = *(const float4*)(gp + c * 8 + q2 * 4);
      float4 b4 = *(const float4*)(bep + c * 8 + q2 * 4);
      os[q2 * 4 + 0] = bfs((vv[c * 8 + q2 * 4 + 0] - mean) * inv * g4.x + b4.x);
      os[q2 * 4 + 1] = bfs((vv[c * 8 + q2 * 4 + 1] - mean) * inv * g4.y + b4.y);
      os[q2 * 4 + 2] = bfs((vv[c * 8 + q2 * 4 + 2] - mean) * inv * g4.z + b4.z);
      os[q2 * 4 + 3] = bfs((vv[c * 8 + q2 * 4 + 3] - mean) * inv * g4.w + b4.w);
    }
    *(short8*)((short*)X + xrow + c * 8) = os;
  }
}

// ---------------------------------------------------------------- MFMA attention (in-place, Q slot)
__global__ __launch_bounds__(256) void k_attn(bf16* __restrict__ QKV) {
  __shared__ short VT[32 * 264];  // V^T [d][key], padded row stride 264
  __shared__ short Pw[4 * 2560];  // per-wave P / O scratch
  int node, h;
  swz_node(blockIdx.x, 4, node, h);
  int tid = threadIdx.x;
  int wave = tid >> 6, lane = tid & 63, quad = lane >> 4, l15 = lane & 15;
  short* sbase = (short*)(QKV + (size_t)node * BB * 384);

  for (int i = tid; i < 4096; i += 256) {
    int key = i >> 4, dp = (i & 15) << 1;
    int two = *(const int*)(sbase + (size_t)key * 384 + 256 + h * 32 + dp);
    VT[dp * 264 + key] = (short)(two & 0xffff);
    VT[(dp + 1) * 264 + key] = (short)(((unsigned)two) >> 16);
  }

  int q0 = wave * 64;
  short8 qf[4];
#pragma unroll
  for (int qt = 0; qt < 4; qt++)
    qf[qt] = *(const short8*)(sbase + (size_t)(q0 + qt * 16 + l15) * 384 + h * 32 + quad * 8);

  __syncthreads();  // VT ready

  floatx4 zz = {0.f, 0.f, 0.f, 0.f};
  floatx4 acc[2][4];
#pragma unroll
  for (int dt = 0; dt < 2; dt++)
#pragma unroll
    for (int qt = 0; qt < 4; qt++) acc[dt][qt] = zz;
  float lp[4] = {0.f, 0.f, 0.f, 0.f};
  const float scale = 0.17677669529663689f;  // 1/sqrt(32)
  short* mypw = &Pw[wave * 2560];

  for (int g = 0; g < 8; g++) {
#pragma unroll
    for (int sub = 0; sub < 2; sub++) {
      int kt = g * 2 + sub;
      short8 kf = *(const short8*)(sbase + (size_t)(kt * 16 + l15) * 384 + 128 + h * 32 + quad * 8);
#pragma unroll
      for (int qt = 0; qt < 4; qt++) {
        floatx4 st = __builtin_amdgcn_mfma_f32_16x16x32_bf16(kf, qf[qt], zz, 0, 0, 0);
        float e0 = __expf(st[0] * scale);
        float e1 = __expf(st[1] * scale);
        float e2 = __expf(st[2] * scale);
        float e3 = __expf(st[3] * scale);
        lp[qt] += (e0 + e1) + (e2 + e3);
        short4a p = {bfs(e0), bfs(e1), bfs(e2), bfs(e3)};
        *(short4a*)(mypw + qt * 640 + l15 * 40 + sub * 16 + quad * 4) = p;
      }
    }
    short8 vf0 = *(const short8*)(&VT[l15 * 264 + g * 32 + quad * 8]);
    short8 vf1 = *(const short8*)(&VT[(16 + l15) * 264 + g * 32 + quad * 8]);
#pragma unroll
    for (int qt = 0; qt < 4; qt++) {
      short8 pf = *(const short8*)(mypw + qt * 640 + l15 * 40 + quad * 8);
      acc[0][qt] = __builtin_amdgcn_mfma_f32_16x16x32_bf16(vf0, pf, acc[0][qt], 0, 0, 0);
      acc[1][qt] = __builtin_amdgcn_mfma_f32_16x16x32_bf16(vf1, pf, acc[1][qt], 0, 0, 0);
    }
  }

  float inv[4];
#pragma unroll
  for (int qt = 0; qt < 4; qt++) {
    float lq = lp[qt];
    lq += __shfl_xor(lq, 16);
    lq += __shfl_xor(lq, 32);
    inv[qt] = 1.0f / lq;
  }

#pragma unroll
  for (int qt = 0; qt < 4; qt++)
#pragma unroll
    for (int dt = 0; dt < 2; dt++)
#pragma unroll
      for (int i = 0; i < 4; i++)
        mypw[(qt * 16 + l15) * 40 + dt * 16 + quad * 4 + i] = bfs(acc[dt][qt][i] * inv[qt]);

#pragma unroll
  for (int r = 0; r < 4; r++) {
    int chunk = r * 64 + lane;
    int query = chunk >> 2, d8 = (chunk & 3) * 8;
    short8 o = *(const short8*)(mypw + query * 40 + d8);
    *(short8*)(sbase + (size_t)(q0 + query) * 384 + h * 32 + d8) = o;
  }
}

// ---------------------------------------------------------------- fold GAT/pred/fc into 4 row-projection vectors
// NOTE: launched AFTER the layer loop — W4/C4 live inside the (then-dead) QKV region.
__global__ __launch_bounds__(256) void k_prep(const float* __restrict__ gatW,
                                              const float* __restrict__ attS,
                                              const float* __restrict__ attD,
                                              const float* __restrict__ predW,
                                              const float* __restrict__ fcW,
                                              const float* __restrict__ fcb,
                                              float* __restrict__ W4,
                                              float* __restrict__ C4) {
  __shared__ float U[4][64];
  int t = threadIdx.x;
  int tt = t >> 6, f = t & 63;
  float u = 0.f;
  if (tt == 0) {
    for (int g = 0; g < 64; g++) u += gatW[g * 64 + f] * attS[g];
  } else if (tt == 1) {
    for (int g = 0; g < 64; g++) u += gatW[g * 64 + f] * attD[g];
  } else if (tt == 2) {
    for (int g = 0; g < 64; g++) u += gatW[g * 64 + f] * predW[g];
  } else {
    for (int g = 0; g < 64; g++) u += gatW[g * 64 + f] * predW[64 + g];
  }
  U[tt][f] = u;
  __syncthreads();
  for (int idx = t; idx < 512; idx += 256) {
    int v = idx >> 7, d = idx & 127;
    float w = 0.f;
#pragma unroll
    for (int ff = 0; ff < 64; ff++) w += fcW[ff * 128 + d] * U[v][ff];
    W4[v * 128 + d] = w;
  }
  if (t < 4) {
    float c = 0.f;
#pragma unroll
    for (int ff = 0; ff < 64; ff++) c += fcb[ff] * U[t][ff];
    C4[t] = c;
  }
}

// ---------------------------------------------------------------- per-row 4 dot products over X
__global__ __launch_bounds__(256) void k_rows(const bf16* __restrict__ X,
                                              const float* __restrict__ W4,
                                              const float* __restrict__ C4,
                                              float* __restrict__ AS,
                                              float* __restrict__ ADv,
                                              float* __restrict__ HW0,
                                              float* __restrict__ HW1) {
  __shared__ float Wl[512];
  int t = threadIdx.x;
  Wl[t] = W4[t];
  Wl[t + 256] = W4[t + 256];
  __syncthreads();
  int wave = t >> 6, lane = t & 63;
  int rrow = lane >> 3, sub = lane & 7;
  int row = blockIdx.x * 32 + wave * 8 + rrow;
  const short* xp = (const short*)(X + (size_t)row * DD) + sub * 16;
  short8 a = *(const short8*)xp;
  short8 b = *(const short8*)(xp + 8);
  float a0 = 0.f, a1 = 0.f, a2 = 0.f, a3 = 0.f;
#pragma unroll
  for (int j = 0; j < 8; j++) {
    float xf = b2f(a[j]);
    int col = sub * 16 + j;
    a0 += xf * Wl[col];
    a1 += xf * Wl[128 + col];
    a2 += xf * Wl[256 + col];
    a3 += xf * Wl[384 + col];
  }
#pragma unroll
  for (int j = 0; j < 8; j++) {
    float xf = b2f(b[j]);
    int col = sub * 16 + 8 + j;
    a0 += xf * Wl[col];
    a1 += xf * Wl[128 + col];
    a2 += xf * Wl[256 + col];
    a3 += xf * Wl[384 + col];
  }
#pragma unroll
  for (int off = 1; off < 8; off <<= 1) {
    a0 += __shfl_xor(a0, off);
    a1 += __shfl_xor(a1, off);
    a2 += __shfl_xor(a2, off);
    a3 += __shfl_xor(a3, off);
  }
  if (sub == 0) {
    AS[row] = a0 + C4[0];
    ADv[row] = a1 + C4[1];
    HW0[row] = a2 + C4[2];
    HW1[row] = a3 + C4[3];
  }
}

// ---------------------------------------------------------------- GAT: one block per batch b
// Block owns its 200-node segment exclusively -> LDS accumulation (ds_add_f32),
// no global atomics, no NUM/DEN buffers; finalize fused in-block.
__global__ __launch_bounds__(256) void k_gat(const int* __restrict__ EI,
                                             const float* __restrict__ AS,
                                             const float* __restrict__ ADv,
                                             const float* __restrict__ HW0,
                                             const float* __restrict__ HW1,
                                             const float* __restrict__ gatB,
                                             const float* __restrict__ predW,
                                             const float* __restrict__ predB,
                                             float* __restrict__ OUT) {
  __shared__ float sAS[NN], sAD[NN], sH0[NN], sH1[NN];
  __shared__ float n0[NN], n1[NN], den[NN];
  __shared__ float cc[2];
  int b = blockIdx.x;
  int t = threadIdx.x;
  int base = b * NN;
  for (int i = t; i < NN; i += 256) {
    sAS[i] = AS[base + i];
    sAD[i] = ADv[base + i];
    sH0[i] = HW0[base + i];
    sH1[i] = HW1[base + i];
    n0[i] = 0.f;
    n1[i] = 0.f;
    den[i] = 0.f;
  }
  if (t < 64) {
    float p0 = gatB[t] * predW[t];
    float p1 = gatB[t] * predW[64 + t];
#pragma unroll
    for (int off = 32; off; off >>= 1) {
      p0 += __shfl_down(p0, off);
      p1 += __shfl_down(p1, off);
    }
    if (t == 0) {
      cc[0] = p0 + predB[0];
      cc[1] = p1 + predB[1];
    }
  }
  __syncthreads();

  for (int i = t; i < NE + NN; i += 256) {
    int s, d;
    if (i < NE) {
      s = EI[i];
      d = EI[NE + i];
    } else {
      s = d = i - NE;  // self loop
    }
    float ev = sAS[s] + sAD[d];
    float lr = ev > 0.f ? ev : 0.2f * ev;
    float w = __expf(lr);
    atomicAdd(&n0[d], w * sH0[s]);
    atomicAdd(&n1[d], w * sH1[s]);
    atomicAdd(&den[d], w);
  }
  __syncthreads();

  for (int i = t; i < NN; i += 256) {
    float inv = 1.0f / (den[i] + 1e-16f);
    OUT[2 * (base + i)] = n0[i] * inv + cc[0];
    OUT[2 * (base + i) + 1] = n1[i] * inv + cc[1];
  }
}

// ================================================================ launch
extern "C" void kernel_launch(void* const* d_in, const int* in_sizes, int n_in,
                              void* d_out, int out_size, void* d_ws, size_t ws_size,
                              hipStream_t stream) {
  const float* x = (const float*)d_in[0];
  const int* ei = (const int*)d_in[1];
  const float* Wqkv = (const float*)d_in[2];
  const float* bqkv = (const float*)d_in[3];
  const float* Wo = (const float*)d_in[4];
  const float* bo = (const float*)d_in[5];
  const float* g1 = (const float*)d_in[6];
  const float* be1 = (const float*)d_in[7];
  const float* fW1 = (const float*)d_in[8];
  const float* fb1 = (const float*)d_in[9];
  const float* fW2 = (const float*)d_in[10];
  const float* fb2 = (const float*)d_in[11];
  const float* g2 = (const float*)d_in[12];
  const float* be2 = (const float*)d_in[13];
  const float* fcW = (const float*)d_in[14];
  const float* fcb = (const float*)d_in[15];
  const float* gatW = (const float*)d_in[16];
  const float* attS = (const float*)d_in[17];
  const float* attD = (const float*)d_in[18];
  const float* gatB = (const float*)d_in[19];
  const float* predW = (const float*)d_in[20];
  const float* predB = (const float*)d_in[21];

  const size_t NEED = 52428800;
  if (ws_size < NEED) return;  // signature: absmax == max|ref|

  char* ws = (char*)d_ws;
  bf16* X = (bf16*)(ws);                  // [N][B][128]   0 .. 13,107,200
  bf16* QKV = (bf16*)(ws + 13107200);     // [N][B][384]  .. 52,428,800
  float* W4 = (float*)(ws + 40960000);    // [4][128]  (written AFTER loop; QKV dead)
  float* C4 = (float*)(ws + 40962048);    // [4]
  float* AS = (float*)(ws + 47513600);    // [51200]
  float* ADv = (float*)(ws + 47718400);   // [51200]
  float* HW0 = (float*)(ws + 47923200);   // [51200]
  float* HW1 = (float*)(ws + 48128000);   // [51200]

  k_transpose<<<25600, 256, 0, stream>>>(x, X);

  for (int l = 0; l < LL; l++) {
    size_t w3o = (size_t)l * 384 * DD, b3o = (size_t)l * 384;
    size_t wso = (size_t)l * DD * DD, bso = (size_t)l * DD;
    k_gemm64<4><<<6 * NN, 256, 0, stream>>>(X, Wqkv, bqkv, QKV, 384, DD,
                                            w3o, LL * 384 * DD, b3o, LL * 384, 0, 6);
    k_attn<<<NN * 4, 256, 0, stream>>>(QKV);
    k_lngemm<<<4 * NN, 256, 0, stream>>>(QKV, 384, Wo, bo, X, g1, be1,
                                         wso, LL * DD * DD, bso, LL * DD, LL * DD);
    k_gemm64<2><<<4 * NN, 256, 0, stream>>>(X, fW1, fb1, QKV, 128, DD,
                                            wso, LL * DD * DD, bso, LL * DD, 1, 2);
    k_lngemm<<<4 * NN, 256, 0, stream>>>(QKV, 128, fW2, fb2, X, g2, be2,
                                         wso, LL * DD * DD, bso, LL * DD, LL * DD);
  }

  // QKV dead from here on: W4/C4 (inside the old QKV region) are now safe.
  k_prep<<<1, 256, 0, stream>>>(gatW, attS, attD, predW, fcW, fcb, W4, C4);
  k_rows<<<1600, 256, 0, stream>>>(X, W4, C4, AS, ADv, HW0, HW1);
  k_gat<<<BB, 256, 0, stream>>>(ei, AS, ADv, HW0, HW1, gatB, predW, predB,
                                (float*)d_out);
}